// Round 8
// baseline (425.777 us; speedup 1.0000x reference)
//
#include <hip/hip_runtime.h>
#include <math.h>

#define CORNER_L 0.05f

typedef float f4 __attribute__((ext_vector_type(4)));

constexpr int THREADS = 256;
constexpr int GROUPS  = 1024;
constexpr int CQ = 3, PQ = 2;                    // class:pose block ratio per group
constexpr int CBLOCKS = CQ * GROUPS;             // 3072
constexpr int PBLOCKS = PQ * GROUPS;             // 2048
constexpr int TOTAL_BLOCKS = CBLOCKS + PBLOCKS;  // 5120

// Fully scalar, pointer-free pose distance for one element pair.
__device__ __forceinline__ float pose_elem(
    float py, float pp_, float pr, float ptx, float pty, float ptz,
    float ty, float tp_, float tr, float ttx, float tty, float ttz)
{
    float sy1 = __sinf(py),  cy1 = __cosf(py);
    float sp1 = __sinf(pp_), cp1 = __cosf(pp_);
    float sr1 = __sinf(pr),  cr1 = __cosf(pr);
    float sy2 = __sinf(ty),  cy2 = __cosf(ty);
    float sp2 = __sinf(tp_), cp2 = __cosf(tp_);
    float sr2 = __sinf(tr),  cr2 = __cosf(tr);

    float a0 = CORNER_L * (cy1 * cp1 - cy2 * cp2);
    float a1 = CORNER_L * ((cy1 * sp1 * sr1 - sy1 * cr1) - (cy2 * sp2 * sr2 - sy2 * cr2));
    float a2 = CORNER_L * ((cy1 * sp1 * cr1 + sy1 * sr1) - (cy2 * sp2 * cr2 + sy2 * sr2));
    float b0 = CORNER_L * (sy1 * cp1 - sy2 * cp2);
    float b1 = CORNER_L * ((sy1 * sp1 * sr1 + cy1 * cr1) - (sy2 * sp2 * sr2 + cy2 * cr2));
    float b2 = CORNER_L * ((sy1 * sp1 * cr1 - cy1 * sr1) - (sy2 * sp2 * cr2 - cy2 * sr2));
    float c0 = CORNER_L * (sp2 - sp1);
    float c1 = CORNER_L * (cp1 * sr1 - cp2 * sr2);
    float c2 = CORNER_L * (cp1 * cr1 - cp2 * cr2);
    float dtx = ptx - ttx;
    float dty = pty - tty;
    float dtz = ptz - ttz;

    float nsum = 0.0f;
    #pragma unroll
    for (int s = 0; s < 8; ++s) {
        float sx = (s & 4) ? 1.0f : -1.0f;
        float sy = (s & 2) ? 1.0f : -1.0f;
        float sz = (s & 1) ? 1.0f : -1.0f;
        float d0 = sx * a0 + sy * a1 + sz * a2 + dtx;
        float d1 = sx * b0 + sy * b1 + sz * b2 + dty;
        float d2 = sx * c0 + sy * c1 + sz * c2 + dtz;
        nsum += __builtin_amdgcn_sqrtf(d0 * d0 + d1 * d1 + d2 * d2);
    }
    return nsum;
}

// ws layout: [0..TOTAL_BLOCKS) per-block partials (class then pose),
//            ws[TOTAL_BLOCKS] = done-counter (as unsigned, zeroed by memset).
__global__ __launch_bounds__(THREADS) void pose_loss_fused(
    const f4* __restrict__ pp4, const f4* __restrict__ pc4,
    const f4* __restrict__ tp4, const f4* __restrict__ tc4,
    float* __restrict__ ws, float* __restrict__ out,
    int n4, float inv_pose, float inv_class)
{
    const int tid = threadIdx.x;
    const int g   = blockIdx.x;
    const int grp = g / 5;
    const int r   = g - grp * 5;

    float acc = 0.0f;
    int out_idx;

    if (r < CQ) {
        // ---------- class MSE: grid-stride, unrolled x2 for MLP ----------
        const int cb = grp * CQ + r;                 // 0..3071
        const size_t G = (size_t)CBLOCKS * THREADS;
        float acc1 = 0.0f;
        for (size_t i = (size_t)cb * THREADS + tid; i < (size_t)n4; i += 2 * G) {
            f4 p0 = __builtin_nontemporal_load(pc4 + i);
            f4 t0 = __builtin_nontemporal_load(tc4 + i);
            if (i + G < (size_t)n4) {
                f4 p1 = __builtin_nontemporal_load(pc4 + i + G);
                f4 t1 = __builtin_nontemporal_load(tc4 + i + G);
                f4 d1 = p1 - t1;
                acc1 += d1.x * d1.x + d1.y * d1.y + d1.z * d1.z + d1.w * d1.w;
            }
            f4 d0 = p0 - t0;
            acc += d0.x * d0.x + d0.y * d0.y + d0.z * d0.z + d0.w * d0.w;
        }
        acc += acc1;
        out_idx = cb;
    } else {
        // ---------- pose: one-shot 3 f4/array per thread, 2 elements ----------
        const int pb = grp * PQ + (r - CQ);          // 0..2047
        const size_t gtid = (size_t)pb * THREADS + tid;
        const size_t f = gtid * 3;
        f4 P0 = __builtin_nontemporal_load(pp4 + f);
        f4 P1 = __builtin_nontemporal_load(pp4 + f + 1);
        f4 P2 = __builtin_nontemporal_load(pp4 + f + 2);
        f4 T0 = __builtin_nontemporal_load(tp4 + f);
        f4 T1 = __builtin_nontemporal_load(tp4 + f + 1);
        f4 T2 = __builtin_nontemporal_load(tp4 + f + 2);
        acc += pose_elem(P0.x, P0.y, P0.z, P0.w, P1.x, P1.y,
                         T0.x, T0.y, T0.z, T0.w, T1.x, T1.y);
        acc += pose_elem(P1.z, P1.w, P2.x, P2.y, P2.z, P2.w,
                         T1.z, T1.w, T2.x, T2.y, T2.z, T2.w);
        out_idx = CBLOCKS + pb;
    }

    // ---------- block reduction ----------
    #pragma unroll
    for (int off = 32; off > 0; off >>= 1) acc += __shfl_down(acc, off);
    __shared__ float red[4];
    const int lane = tid & 63, wave = tid >> 6;
    if (lane == 0) red[wave] = acc;
    __syncthreads();

    // ---------- partial store + last-block finalize ----------
    __shared__ bool s_last;
    if (tid == 0) {
        ws[out_idx] = red[0] + red[1] + red[2] + red[3];
        __threadfence();                               // partial visible device-wide
        unsigned old = atomicAdd((unsigned*)(ws + TOTAL_BLOCKS), 1u);
        s_last = (old == (unsigned)(TOTAL_BLOCKS - 1));
    }
    __syncthreads();

    if (s_last) {
        __threadfence();                               // acquire: see all partials
        float c = 0.0f, p = 0.0f;
        for (int k = tid; k < CBLOCKS; k += THREADS) c += ws[k];
        for (int k = tid; k < PBLOCKS; k += THREADS) p += ws[CBLOCKS + k];
        #pragma unroll
        for (int off = 32; off > 0; off >>= 1) {
            p += __shfl_down(p, off);
            c += __shfl_down(c, off);
        }
        __shared__ float r_p[4], r_c[4];
        if (lane == 0) { r_p[wave] = p; r_c[wave] = c; }
        __syncthreads();
        if (tid == 0) {
            float lp = (r_p[0] + r_p[1] + r_p[2] + r_p[3]) * inv_pose;
            float lc = (r_c[0] + r_c[1] + r_c[2] + r_c[3]) * inv_class;
            out[0] = lp + lc;
            out[1] = lp;
            out[2] = lc;
        }
    }
}

extern "C" void kernel_launch(void* const* d_in, const int* in_sizes, int n_in,
                              void* d_out, int out_size, void* d_ws, size_t ws_size,
                              hipStream_t stream) {
    const f4* pred_pose    = (const f4*)d_in[0];
    const f4* pred_class   = (const f4*)d_in[1];
    const f4* target_pose  = (const f4*)d_in[2];
    const f4* target_class = (const f4*)d_in[3];
    float* out = (float*)d_out;
    float* ws  = (float*)d_ws;

    const int B  = in_sizes[0] / 6;
    const int n4 = B * 4;   // float4 count per class array

    // zero only the done-counter (partials are fully overwritten each launch)
    hipMemsetAsync(ws + TOTAL_BLOCKS, 0, sizeof(unsigned), stream);

    const float inv_pose  = 1.0f / (8.0f  * (float)B);
    const float inv_class = 1.0f / (16.0f * (float)B);

    pose_loss_fused<<<TOTAL_BLOCKS, THREADS, 0, stream>>>(
        pred_pose, pred_class, target_pose, target_class, ws, out,
        n4, inv_pose, inv_class);
}

// Round 9
// 174.807 us; speedup vs baseline: 2.4357x; 2.4357x over previous
//
#include <hip/hip_runtime.h>
#include <math.h>

#define CORNER_L 0.05f

typedef float f4 __attribute__((ext_vector_type(4)));

constexpr int THREADS = 256;
constexpr int GROUPS  = 1024;
constexpr int CQ = 4, PQ = 2;                    // class:pose blocks per group
constexpr int CBLOCKS = CQ * GROUPS;             // 4096 -> exactly 4 class iters
constexpr int PBLOCKS = PQ * GROUPS;             // 2048 -> 2 pose elems/thread
constexpr int TOTAL_BLOCKS = CBLOCKS + PBLOCKS;  // 6144

// Fully scalar, pointer-free pose distance for one element pair.
__device__ __forceinline__ float pose_elem(
    float py, float pp_, float pr, float ptx, float pty, float ptz,
    float ty, float tp_, float tr, float ttx, float tty, float ttz)
{
    float sy1 = __sinf(py),  cy1 = __cosf(py);
    float sp1 = __sinf(pp_), cp1 = __cosf(pp_);
    float sr1 = __sinf(pr),  cr1 = __cosf(pr);
    float sy2 = __sinf(ty),  cy2 = __cosf(ty);
    float sp2 = __sinf(tp_), cp2 = __cosf(tp_);
    float sr2 = __sinf(tr),  cr2 = __cosf(tr);

    float a0 = CORNER_L * (cy1 * cp1 - cy2 * cp2);
    float a1 = CORNER_L * ((cy1 * sp1 * sr1 - sy1 * cr1) - (cy2 * sp2 * sr2 - sy2 * cr2));
    float a2 = CORNER_L * ((cy1 * sp1 * cr1 + sy1 * sr1) - (cy2 * sp2 * cr2 + sy2 * sr2));
    float b0 = CORNER_L * (sy1 * cp1 - sy2 * cp2);
    float b1 = CORNER_L * ((sy1 * sp1 * sr1 + cy1 * cr1) - (sy2 * sp2 * sr2 + cy2 * cr2));
    float b2 = CORNER_L * ((sy1 * sp1 * cr1 - cy1 * sr1) - (sy2 * sp2 * cr2 - cy2 * sr2));
    float c0 = CORNER_L * (sp2 - sp1);
    float c1 = CORNER_L * (cp1 * sr1 - cp2 * sr2);
    float c2 = CORNER_L * (cp1 * cr1 - cp2 * cr2);
    float dtx = ptx - ttx;
    float dty = pty - tty;
    float dtz = ptz - ttz;

    float nsum = 0.0f;
    #pragma unroll
    for (int s = 0; s < 8; ++s) {
        float sx = (s & 4) ? 1.0f : -1.0f;
        float sy = (s & 2) ? 1.0f : -1.0f;
        float sz = (s & 1) ? 1.0f : -1.0f;
        float d0 = sx * a0 + sy * a1 + sz * a2 + dtx;
        float d1 = sx * b0 + sy * b1 + sz * b2 + dty;
        float d2 = sx * c0 + sy * c1 + sz * c2 + dtz;
        nsum += __builtin_amdgcn_sqrtf(d0 * d0 + d1 * d1 + d2 * d2);
    }
    return nsum;
}

// Block-specialized fused kernel: per group of 6 blocks, 4 stream class MSE
// (exactly 4 unrolled iterations each, no bounds checks), 2 run the pose path.
__global__ __launch_bounds__(THREADS) void pose_loss_fused(
    const f4* __restrict__ pp4, const f4* __restrict__ pc4,
    const f4* __restrict__ tp4, const f4* __restrict__ tc4,
    float* __restrict__ ws)
{
    const int tid = threadIdx.x;
    const int g   = blockIdx.x;
    const int grp = g / 6;
    const int r   = g - grp * 6;

    float acc = 0.0f;
    int out_idx;

    if (r < CQ) {
        // ---------- class MSE: exactly 4 iterations, fully unrolled ----------
        const int cb = grp * CQ + r;                   // 0..4095
        const size_t G = (size_t)CBLOCKS * THREADS;    // 1048576
        size_t i = (size_t)cb * THREADS + tid;
        float a0 = 0.f, a1 = 0.f, a2 = 0.f, a3 = 0.f;
        #pragma unroll
        for (int k = 0; k < 4; ++k) {
            f4 p = __builtin_nontemporal_load(pc4 + i + k * G);
            f4 t = __builtin_nontemporal_load(tc4 + i + k * G);
            f4 d = p - t;
            float s = d.x * d.x + d.y * d.y + d.z * d.z + d.w * d.w;
            if (k == 0) a0 += s; else if (k == 1) a1 += s;
            else if (k == 2) a2 += s; else a3 += s;
        }
        acc = (a0 + a1) + (a2 + a3);
        out_idx = cb;
    } else {
        // ---------- pose: one-shot 3 f4/array per thread, 2 elements ----------
        const int pb = grp * PQ + (r - CQ);            // 0..2047
        const size_t gtid = (size_t)pb * THREADS + tid;
        const size_t f = gtid * 3;
        f4 P0 = __builtin_nontemporal_load(pp4 + f);
        f4 P1 = __builtin_nontemporal_load(pp4 + f + 1);
        f4 P2 = __builtin_nontemporal_load(pp4 + f + 2);
        f4 T0 = __builtin_nontemporal_load(tp4 + f);
        f4 T1 = __builtin_nontemporal_load(tp4 + f + 1);
        f4 T2 = __builtin_nontemporal_load(tp4 + f + 2);
        acc += pose_elem(P0.x, P0.y, P0.z, P0.w, P1.x, P1.y,
                         T0.x, T0.y, T0.z, T0.w, T1.x, T1.y);
        acc += pose_elem(P1.z, P1.w, P2.x, P2.y, P2.z, P2.w,
                         T1.z, T1.w, T2.x, T2.y, T2.z, T2.w);
        out_idx = CBLOCKS + pb;
    }

    // ---------- common block reduction ----------
    #pragma unroll
    for (int off = 32; off > 0; off >>= 1) acc += __shfl_down(acc, off);
    __shared__ float red[4];
    const int lane = tid & 63, wave = tid >> 6;
    if (lane == 0) red[wave] = acc;
    __syncthreads();
    if (tid == 0) ws[out_idx] = red[0] + red[1] + red[2] + red[3];
}

// finalize: ws[0..CBLOCKS) = class partials, ws[CBLOCKS..TOTAL) = pose partials
__global__ __launch_bounds__(THREADS) void pose_loss_finalize(
    const float* __restrict__ ws, float* __restrict__ out,
    float inv_pose, float inv_class)
{
    float c = 0.0f, p = 0.0f;
    for (int k = threadIdx.x; k < CBLOCKS; k += THREADS) c += ws[k];
    for (int k = threadIdx.x; k < PBLOCKS; k += THREADS) p += ws[CBLOCKS + k];
    #pragma unroll
    for (int off = 32; off > 0; off >>= 1) {
        p += __shfl_down(p, off);
        c += __shfl_down(c, off);
    }
    __shared__ float r_p[4], r_c[4];
    const int lane = threadIdx.x & 63, wave = threadIdx.x >> 6;
    if (lane == 0) { r_p[wave] = p; r_c[wave] = c; }
    __syncthreads();
    if (threadIdx.x == 0) {
        float lp = (r_p[0] + r_p[1] + r_p[2] + r_p[3]) * inv_pose;
        float lc = (r_c[0] + r_c[1] + r_c[2] + r_c[3]) * inv_class;
        out[0] = lp + lc;
        out[1] = lp;
        out[2] = lc;
    }
}

extern "C" void kernel_launch(void* const* d_in, const int* in_sizes, int n_in,
                              void* d_out, int out_size, void* d_ws, size_t ws_size,
                              hipStream_t stream) {
    const f4* pred_pose    = (const f4*)d_in[0];
    const f4* pred_class   = (const f4*)d_in[1];
    const f4* target_pose  = (const f4*)d_in[2];
    const f4* target_class = (const f4*)d_in[3];
    float* out = (float*)d_out;
    float* ws  = (float*)d_ws;

    const int B = in_sizes[0] / 6;

    pose_loss_fused<<<TOTAL_BLOCKS, THREADS, 0, stream>>>(
        pred_pose, pred_class, target_pose, target_class, ws);

    const float inv_pose  = 1.0f / (8.0f  * (float)B);
    const float inv_class = 1.0f / (16.0f * (float)B);
    pose_loss_finalize<<<1, THREADS, 0, stream>>>(ws, out, inv_pose, inv_class);
}